// Round 3
// baseline (241.098 us; speedup 1.0000x reference)
//
#include <hip/hip_runtime.h>

typedef __attribute__((ext_vector_type(8))) short bf16x8;
typedef __attribute__((ext_vector_type(4))) float f32x4;

__device__ __forceinline__ unsigned short f2bf(float f) {
  union { float f; unsigned u; } v; v.f = f;
  unsigned r = v.u + 0x7fffu + ((v.u >> 16) & 1u);
  return (unsigned short)(r >> 16);
}

__device__ __forceinline__ void gatomic_fadd(float* p, float v) {
#if __has_builtin(__builtin_amdgcn_global_atomic_fadd_f32)
  __builtin_amdgcn_global_atomic_fadd_f32((__attribute__((address_space(1))) float*)p, v);
#else
  atomicAdd(p, v);
#endif
}

// ---- x: f32 -> bf16 (vectorized) + out := bias ----
__global__ void cvt_x_bias_kernel(const float* __restrict__ in, unsigned short* __restrict__ x_bf,
                                  const float* __restrict__ bias, float* __restrict__ out) {
  int i = blockIdx.x * blockDim.x + threadIdx.x;  // 1M float4 slots
  float4 v = ((const float4*)in)[i];
  ushort4 o; o.x = f2bf(v.x); o.y = f2bf(v.y); o.z = f2bf(v.z); o.w = f2bf(v.w);
  ((ushort4*)x_bf)[i] = o;
  ((float4*)out)[i] = ((const float4*)bias)[i & 255];  // out[4096][1024] = bias
}

// ---- per-expert transpose+convert: in [R][C] f32 -> out [C][R] bf16 ----
__global__ void transpose_cvt_kernel(const float* __restrict__ in, unsigned short* __restrict__ out,
                                     int R, int C) {
  __shared__ float t[32][33];
  size_t eo = (size_t)blockIdx.z * R * C;
  const float* src = in + eo;
  unsigned short* dst = out + eo;
  int c0 = blockIdx.x * 32, r0 = blockIdx.y * 32;
  int tx = threadIdx.x, ty = threadIdx.y;  // block (32,8)
#pragma unroll
  for (int i = 0; i < 32; i += 8)
    t[ty + i][tx] = src[(size_t)(r0 + ty + i) * C + (c0 + tx)];
  __syncthreads();
#pragma unroll
  for (int i = 0; i < 32; i += 8)
    dst[(size_t)(c0 + ty + i) * R + (r0 + tx)] = f2bf(t[tx][ty + i]);
}

// ---- per-expert compaction with complement tail:
// rows[z][0..cnt) = active b's; rows[z][cnt..4096) = masked b's ----
__global__ void compact_kernel(const int* __restrict__ mask, int* __restrict__ rows,
                               int* __restrict__ counts) {
  int z = blockIdx.x;
  __shared__ int cnt, mcnt;
  if (threadIdx.x == 0) { cnt = 0; mcnt = 0; }
  __syncthreads();
  int* rz = rows + (size_t)z * 4096;
  for (int i = threadIdx.x; i < 4096; i += blockDim.x) {
    bool m = mask[(size_t)i * 16 + z] != 0;
    unsigned long long bal = __ballot(m);
    int lane = threadIdx.x & 63;
    int pa = __popcll(bal & ((1ull << lane) - 1ull));
    int ta = __popcll(bal);
    int base_a, base_m;
    if (lane == 0) { base_a = atomicAdd(&cnt, ta); base_m = atomicAdd(&mcnt, 64 - ta); }
    base_a = __shfl(base_a, 0);
    base_m = __shfl(base_m, 0);
    int pm = lane - pa;  // prefix among masked lanes
    if (m) rz[base_a + pa] = i;
    else   rz[4095 - (base_m + pm)] = i;
  }
  __syncthreads();
  if (threadIdx.x == 0) counts[z] = cnt;
}

// ---- LDS staging, 128x64 bf16 tile, XOR swizzle phys = log ^ ((row&7)<<4) ----
__device__ __forceinline__ void stage_tile(const unsigned short* __restrict__ src,
                                           size_t row_stride, int row0, int k0,
                                           unsigned short* lds) {
  int t = threadIdx.x;
  int lane = t & 63;
  int w = t >> 6;
#pragma unroll
  for (int i = 0; i < 4; ++i) {
    int chunk = w * 4 + i;
    int row = chunk * 8 + (lane >> 3);
    int glog = (lane & 7) ^ (row & 7);
    const unsigned short* g = src + (size_t)(row0 + row) * row_stride + (size_t)(k0 + glog * 8);
    __builtin_amdgcn_global_load_lds((const __attribute__((address_space(1))) unsigned int*)g,
                                     (__attribute__((address_space(3))) unsigned int*)(lds + chunk * 512),
                                     16, 0, 0);
  }
}

// gather variant: per-lane row index (global source per-lane is legal)
__device__ __forceinline__ void stage_tile_gather(const unsigned short* __restrict__ src,
                                                  const int* __restrict__ rowsS, int k0,
                                                  unsigned short* lds) {
  int t = threadIdx.x;
  int lane = t & 63;
  int w = t >> 6;
#pragma unroll
  for (int i = 0; i < 4; ++i) {
    int chunk = w * 4 + i;
    int row = chunk * 8 + (lane >> 3);
    int glog = (lane & 7) ^ (row & 7);
    const unsigned short* g = src + (size_t)rowsS[row] * 1024 + (size_t)(k0 + glog * 8);
    __builtin_amdgcn_global_load_lds((const __attribute__((address_space(1))) unsigned int*)g,
                                     (__attribute__((address_space(3))) unsigned int*)(lds + chunk * 512),
                                     16, 0, 0);
  }
}

__device__ __forceinline__ bf16x8 read_frag(const unsigned short* lds, int row, int gb) {
  int phys = (row * 128 + gb) ^ ((row & 7) << 4);
  return *(const bf16x8*)((const char*)lds + phys);
}

// MODE 0: pre[z][r][m] (bf16) = x_bf[rows[z][r]] . A_t[z][512 m][1024 i]^T   (K=1024)
// MODE 1: inner[rows[z][r]][z][h] = pre[z][r] . B_t[z][1024 h][512 m]^T (K=512)
//         + zero-fill masked rows (tail of rows list) + atomic-add into out
template <int MODE>
__global__ __launch_bounds__(256)
void moe_gemm_kernel(const unsigned short* __restrict__ X,
                     const unsigned short* __restrict__ W,
                     unsigned short* __restrict__ pre_out,
                     float* __restrict__ inner_out,
                     float* __restrict__ out,
                     const int* __restrict__ rows,
                     const int* __restrict__ counts) {
  const int z = blockIdx.z;
  const int cnt = counts[z];
  const int tb = blockIdx.y * 128;
  const int tn = blockIdx.x * 128;
  const int t = threadIdx.x;

  if (MODE == 0 && tb >= cnt) return;  // masked rows need no pre

  __shared__ unsigned short Xs[128 * 64];
  __shared__ unsigned short Ws[128 * 64];
  __shared__ int rowsS[128];

  if (t < 128) rowsS[t] = rows[(size_t)z * 4096 + tb + t];
  __syncthreads();

  if (MODE == 1 && tb >= cnt) {
    // pure zero-fill block: rowsS are all masked b's
    const float4 z4 = {0.f, 0.f, 0.f, 0.f};
#pragma unroll
    for (int it = 0; it < 16; ++it) {
      int rl = it * 8 + (t >> 5);
      int b = rowsS[rl];
      ((float4*)(inner_out + (size_t)b * (16 * 1024) + (size_t)z * 1024 + tn))[t & 31] = z4;
    }
    return;
  }

  const int lane = t & 63;
  const int wv = t >> 6;
  const int wr = (wv >> 1) * 64;
  const int wc = (wv & 1) * 64;
  const int fr = lane & 15;
  const int fg = lane >> 4;

  const unsigned short* Xbase;
  const unsigned short* Wbase;
  size_t xstride, wstride;
  int nkt;
  if (MODE == 0) {
    Xbase = X;                            xstride = 1024;   // gathered
    Wbase = W + (size_t)z * 512 * 1024;   wstride = 1024;
    nkt = 16;
  } else {
    Xbase = X + (size_t)z * 4096 * 512;   xstride = 512;    // compact-contiguous
    Wbase = W + (size_t)z * 1024 * 512;   wstride = 512;
    nkt = 8;
  }

  f32x4 acc[4][4] = {};

  for (int kt = 0; kt < nkt; ++kt) {
    if (kt) __syncthreads();
    if (MODE == 0)
      stage_tile_gather(Xbase, rowsS, kt * 64, Xs);
    else
      stage_tile(Xbase, xstride, tb, kt * 64, Xs);
    stage_tile(Wbase, wstride, tn, kt * 64, Ws);
    __syncthreads();
#pragma unroll
    for (int kk = 0; kk < 2; ++kk) {
      const int gb = kk * 64 + fg * 16;
      bf16x8 xf[4], wf[4];
#pragma unroll
      for (int i = 0; i < 4; ++i) {
        xf[i] = read_frag(Xs, wr + i * 16 + fr, gb);
        wf[i] = read_frag(Ws, wc + i * 16 + fr, gb);
      }
#pragma unroll
      for (int mi = 0; mi < 4; ++mi)
#pragma unroll
        for (int ni = 0; ni < 4; ++ni)
          acc[mi][ni] = __builtin_amdgcn_mfma_f32_16x16x32_bf16(xf[mi], wf[ni], acc[mi][ni], 0, 0, 0);
    }
  }

  // C/D layout: col = lane&15, row = (lane>>4)*4 + j
  if (MODE == 0) {
#pragma unroll
    for (int mi = 0; mi < 4; ++mi) {
#pragma unroll
      for (int j = 0; j < 4; ++j) {
        int rl = wr + mi * 16 + fg * 4 + j;
        size_t rowbase = (size_t)z * 4096 * 512 + (size_t)(tb + rl) * 512;
#pragma unroll
        for (int ni = 0; ni < 4; ++ni) {
          int m = tn + wc + ni * 16 + fr;
          pre_out[rowbase + m] = f2bf(acc[mi][ni][j]);  // rows >= cnt: finite garbage, overwritten/ignored downstream
        }
      }
    }
  } else {
#pragma unroll
    for (int mi = 0; mi < 4; ++mi) {
#pragma unroll
      for (int j = 0; j < 4; ++j) {
        int rl = wr + mi * 16 + fg * 4 + j;
        int b = rowsS[rl];
        size_t rowbase = (size_t)b * (16 * 1024) + (size_t)z * 1024;
        if (tb + rl < cnt) {
#pragma unroll
          for (int ni = 0; ni < 4; ++ni) {
            int h = tn + wc + ni * 16 + fr;
            float val = acc[mi][ni][j];
            inner_out[rowbase + h] = val;
            gatomic_fadd(out + (size_t)b * 1024 + h, val);
          }
        } else {  // boundary block: masked rows -> zeros
#pragma unroll
          for (int ni = 0; ni < 4; ++ni) {
            int h = tn + wc + ni * 16 + fr;
            inner_out[rowbase + h] = 0.f;
          }
        }
      }
    }
  }
}

extern "C" void kernel_launch(void* const* d_in, const int* in_sizes, int n_in,
                              void* d_out, int out_size, void* d_ws, size_t ws_size,
                              hipStream_t stream) {
  const float* x    = (const float*)d_in[0];
  const int*   mask = (const int*)d_in[1];
  const float* A    = (const float*)d_in[2];
  const float* B    = (const float*)d_in[3];
  const float* bias = (const float*)d_in[4];

  float* out   = (float*)d_out;
  float* inner = (float*)d_out + (size_t)4096 * 1024;

  // ws layout: x_bf 8MiB | A_t 16MiB | B_t 16MiB | pre 64MiB | rows 256KiB | counts
  if (ws_size < 109314112ull) return;
  char* ws = (char*)d_ws;
  unsigned short* x_bf = (unsigned short*)ws;
  unsigned short* A_t  = (unsigned short*)(ws + ((size_t)8 << 20));
  unsigned short* B_t  = (unsigned short*)(ws + ((size_t)24 << 20));
  unsigned short* pre  = (unsigned short*)(ws + ((size_t)40 << 20));
  int* rows            = (int*)(ws + ((size_t)104 << 20));
  int* counts          = (int*)(ws + ((size_t)104 << 20) + 262144);

  cvt_x_bias_kernel<<<4096, 256, 0, stream>>>(x, x_bf, bias, out);
  transpose_cvt_kernel<<<dim3(16, 32, 16), dim3(32, 8), 0, stream>>>(A, A_t, 1024, 512);
  transpose_cvt_kernel<<<dim3(32, 16, 16), dim3(32, 8), 0, stream>>>(B, B_t, 512, 1024);
  compact_kernel<<<16, 256, 0, stream>>>(mask, rows, counts);

  moe_gemm_kernel<0><<<dim3(4, 32, 16), 256, 0, stream>>>(x_bf, A_t, pre, nullptr, nullptr, rows, counts);
  moe_gemm_kernel<1><<<dim3(8, 32, 16), 256, 0, stream>>>(pre, B_t, nullptr, inner, out, rows, counts);
}

// Round 4
// 211.226 us; speedup vs baseline: 1.1414x; 1.1414x over previous
//
#include <hip/hip_runtime.h>

typedef __attribute__((ext_vector_type(8))) short bf16x8;
typedef __attribute__((ext_vector_type(4))) float f32x4;

__device__ __forceinline__ unsigned short f2bf(float f) {
  union { float f; unsigned u; } v; v.f = f;
  unsigned r = v.u + 0x7fffu + ((v.u >> 16) & 1u);
  return (unsigned short)(r >> 16);
}

// ---- x: f32 -> bf16, vectorized ----
__global__ void cvt_x_kernel(const float* __restrict__ in, unsigned short* __restrict__ out, int n4) {
  int i = blockIdx.x * blockDim.x + threadIdx.x;
  if (i >= n4) return;
  float4 v = ((const float4*)in)[i];
  ushort4 o; o.x = f2bf(v.x); o.y = f2bf(v.y); o.z = f2bf(v.z); o.w = f2bf(v.w);
  ((ushort4*)out)[i] = o;
}

// ---- per-expert transpose+convert: in [R][C] f32 -> out [C][R] bf16 ----
__global__ void transpose_cvt_kernel(const float* __restrict__ in, unsigned short* __restrict__ out,
                                     int R, int C) {
  __shared__ float t[32][33];
  size_t eo = (size_t)blockIdx.z * R * C;
  const float* src = in + eo;
  unsigned short* dst = out + eo;
  int c0 = blockIdx.x * 32, r0 = blockIdx.y * 32;
  int tx = threadIdx.x, ty = threadIdx.y;  // block (32,8)
#pragma unroll
  for (int i = 0; i < 32; i += 8)
    t[ty + i][tx] = src[(size_t)(r0 + ty + i) * C + (c0 + tx)];
  __syncthreads();
#pragma unroll
  for (int i = 0; i < 32; i += 8)
    dst[(size_t)(c0 + ty + i) * R + (r0 + tx)] = f2bf(t[tx][ty + i]);
}

// ---- per-expert compaction with complement tail:
// rows[z][0..cnt) = active b's; rows[z][cnt..4096) = masked b's ----
__global__ void compact_kernel(const int* __restrict__ mask, int* __restrict__ rows,
                               int* __restrict__ counts) {
  int z = blockIdx.x;
  __shared__ int cnt, mcnt;
  if (threadIdx.x == 0) { cnt = 0; mcnt = 0; }
  __syncthreads();
  int* rz = rows + (size_t)z * 4096;
  for (int i = threadIdx.x; i < 4096; i += blockDim.x) {
    bool m = mask[(size_t)i * 16 + z] != 0;
    unsigned long long bal = __ballot(m);
    int lane = threadIdx.x & 63;
    int pa = __popcll(bal & ((1ull << lane) - 1ull));
    int ta = __popcll(bal);
    int base_a, base_m;
    if (lane == 0) { base_a = atomicAdd(&cnt, ta); base_m = atomicAdd(&mcnt, 64 - ta); }
    base_a = __shfl(base_a, 0);
    base_m = __shfl(base_m, 0);
    int pm = lane - pa;  // prefix among masked lanes
    if (m) rz[base_a + pa] = i;
    else   rz[4095 - (base_m + pm)] = i;
  }
  __syncthreads();
  if (threadIdx.x == 0) counts[z] = cnt;
}

// ---- LDS staging, 128x64 bf16 tile, XOR swizzle phys = log ^ ((row&7)<<4) ----
__device__ __forceinline__ void stage_tile(const unsigned short* __restrict__ src,
                                           size_t row_stride, int row0, int k0,
                                           unsigned short* lds) {
  int t = threadIdx.x;
  int lane = t & 63;
  int w = t >> 6;
#pragma unroll
  for (int i = 0; i < 4; ++i) {
    int chunk = w * 4 + i;
    int row = chunk * 8 + (lane >> 3);
    int glog = (lane & 7) ^ (row & 7);
    const unsigned short* g = src + (size_t)(row0 + row) * row_stride + (size_t)(k0 + glog * 8);
    __builtin_amdgcn_global_load_lds((const __attribute__((address_space(1))) unsigned int*)g,
                                     (__attribute__((address_space(3))) unsigned int*)(lds + chunk * 512),
                                     16, 0, 0);
  }
}

// gather variant: per-lane row index (global source per-lane is legal)
__device__ __forceinline__ void stage_tile_gather(const unsigned short* __restrict__ src,
                                                  const int* __restrict__ rowsS, int k0,
                                                  unsigned short* lds) {
  int t = threadIdx.x;
  int lane = t & 63;
  int w = t >> 6;
#pragma unroll
  for (int i = 0; i < 4; ++i) {
    int chunk = w * 4 + i;
    int row = chunk * 8 + (lane >> 3);
    int glog = (lane & 7) ^ (row & 7);
    const unsigned short* g = src + (size_t)rowsS[row] * 1024 + (size_t)(k0 + glog * 8);
    __builtin_amdgcn_global_load_lds((const __attribute__((address_space(1))) unsigned int*)g,
                                     (__attribute__((address_space(3))) unsigned int*)(lds + chunk * 512),
                                     16, 0, 0);
  }
}

__device__ __forceinline__ bf16x8 read_frag(const unsigned short* lds, int row, int gb) {
  int phys = (row * 128 + gb) ^ ((row & 7) << 4);
  return *(const bf16x8*)((const char*)lds + phys);
}

// MODE 0: pre[z][r][m] (bf16) = x_bf[rows[z][r]] . A_t[z][512 m][1024 i]^T   (K=1024)
// MODE 1: inner[rows[z][r]][z][h] = pre[z][r] . B_t[z][1024 h][512 m]^T (K=512)
//         + zero-fill masked rows (tail of rows list)
template <int MODE>
__global__ __launch_bounds__(256)
void moe_gemm_kernel(const unsigned short* __restrict__ X,
                     const unsigned short* __restrict__ W,
                     unsigned short* __restrict__ pre_out,
                     float* __restrict__ inner_out,
                     const int* __restrict__ rows,
                     const int* __restrict__ counts) {
  const int z = blockIdx.z;
  const int cnt = counts[z];
  const int tb = blockIdx.y * 128;
  const int tn = blockIdx.x * 128;
  const int t = threadIdx.x;

  if (MODE == 0 && tb >= cnt) return;  // masked rows need no pre

  __shared__ unsigned short Xs[128 * 64];
  __shared__ unsigned short Ws[128 * 64];
  __shared__ int rowsS[128];

  if (t < 128) rowsS[t] = rows[(size_t)z * 4096 + tb + t];
  __syncthreads();

  if (MODE == 1 && tb >= cnt) {
    // pure zero-fill block: rowsS are all masked b's
    const float4 z4 = {0.f, 0.f, 0.f, 0.f};
#pragma unroll
    for (int it = 0; it < 16; ++it) {
      int rl = it * 8 + (t >> 5);
      int b = rowsS[rl];
      ((float4*)(inner_out + (size_t)b * (16 * 1024) + (size_t)z * 1024 + tn))[t & 31] = z4;
    }
    return;
  }

  const int lane = t & 63;
  const int wv = t >> 6;
  const int wr = (wv >> 1) * 64;
  const int wc = (wv & 1) * 64;
  const int fr = lane & 15;
  const int fg = lane >> 4;

  const unsigned short* Xbase;
  const unsigned short* Wbase;
  size_t xstride, wstride;
  int nkt;
  if (MODE == 0) {
    Xbase = X;                            xstride = 1024;   // gathered
    Wbase = W + (size_t)z * 512 * 1024;   wstride = 1024;
    nkt = 16;
  } else {
    Xbase = X + (size_t)z * 4096 * 512;   xstride = 512;    // compact-contiguous
    Wbase = W + (size_t)z * 1024 * 512;   wstride = 512;
    nkt = 8;
  }

  f32x4 acc[4][4] = {};

  for (int kt = 0; kt < nkt; ++kt) {
    if (kt) __syncthreads();
    if (MODE == 0)
      stage_tile_gather(Xbase, rowsS, kt * 64, Xs);
    else
      stage_tile(Xbase, xstride, tb, kt * 64, Xs);
    stage_tile(Wbase, wstride, tn, kt * 64, Ws);
    __syncthreads();
#pragma unroll
    for (int kk = 0; kk < 2; ++kk) {
      const int gb = kk * 64 + fg * 16;
      bf16x8 xf[4], wf[4];
#pragma unroll
      for (int i = 0; i < 4; ++i) {
        xf[i] = read_frag(Xs, wr + i * 16 + fr, gb);
        wf[i] = read_frag(Ws, wc + i * 16 + fr, gb);
      }
#pragma unroll
      for (int mi = 0; mi < 4; ++mi)
#pragma unroll
        for (int ni = 0; ni < 4; ++ni)
          acc[mi][ni] = __builtin_amdgcn_mfma_f32_16x16x32_bf16(xf[mi], wf[ni], acc[mi][ni], 0, 0, 0);
    }
  }

  // C/D layout: col = lane&15, row = (lane>>4)*4 + j
  if (MODE == 0) {
#pragma unroll
    for (int mi = 0; mi < 4; ++mi) {
#pragma unroll
      for (int j = 0; j < 4; ++j) {
        int rl = wr + mi * 16 + fg * 4 + j;
        size_t rowbase = (size_t)z * 4096 * 512 + (size_t)(tb + rl) * 512;
#pragma unroll
        for (int ni = 0; ni < 4; ++ni) {
          int m = tn + wc + ni * 16 + fr;
          pre_out[rowbase + m] = f2bf(acc[mi][ni][j]);  // padded slots: finite garbage, discarded downstream
        }
      }
    }
  } else {
#pragma unroll
    for (int mi = 0; mi < 4; ++mi) {
#pragma unroll
      for (int j = 0; j < 4; ++j) {
        int rl = wr + mi * 16 + fg * 4 + j;
        int b = rowsS[rl];
        size_t rowbase = (size_t)b * (16 * 1024) + (size_t)z * 1024;
        if (tb + rl < cnt) {
#pragma unroll
          for (int ni = 0; ni < 4; ++ni) {
            int h = tn + wc + ni * 16 + fr;
            inner_out[rowbase + h] = acc[mi][ni][j];
          }
        } else {  // boundary block: masked rows -> zeros
#pragma unroll
          for (int ni = 0; ni < 4; ++ni) {
            int h = tn + wc + ni * 16 + fr;
            inner_out[rowbase + h] = 0.f;
          }
        }
      }
    }
  }
}

// ---- out[b] = bias + sum_{k: mask[b][k]} inner[b][k]  (masked rows already zero, not read) ----
__global__ __launch_bounds__(256)
void reduce_kernel(const float* __restrict__ inner, const float* __restrict__ bias,
                   const int* __restrict__ mask, float* __restrict__ out) {
  int b = blockIdx.x;
  int t = threadIdx.x;  // 256
  __shared__ int mrow[16];
  if (t < 16) mrow[t] = mask[(size_t)b * 16 + t];
  __syncthreads();
  float4 s = ((const float4*)bias)[t];
  const float4* ip = (const float4*)(inner + (size_t)b * (16 * 1024)) + t;
#pragma unroll
  for (int k = 0; k < 16; ++k) {
    if (mrow[k]) {
      float4 v = ip[(size_t)k * 256];
      s.x += v.x; s.y += v.y; s.z += v.z; s.w += v.w;
    }
  }
  ((float4*)out)[(size_t)b * 256 + t] = s;
}

extern "C" void kernel_launch(void* const* d_in, const int* in_sizes, int n_in,
                              void* d_out, int out_size, void* d_ws, size_t ws_size,
                              hipStream_t stream) {
  const float* x    = (const float*)d_in[0];
  const int*   mask = (const int*)d_in[1];
  const float* A    = (const float*)d_in[2];
  const float* B    = (const float*)d_in[3];
  const float* bias = (const float*)d_in[4];

  float* out   = (float*)d_out;
  float* inner = (float*)d_out + (size_t)4096 * 1024;

  // ws layout: x_bf 8MiB | A_t 16MiB | B_t 16MiB | pre 64MiB | rows 256KiB | counts
  if (ws_size < 109314112ull) return;
  char* ws = (char*)d_ws;
  unsigned short* x_bf = (unsigned short*)ws;
  unsigned short* A_t  = (unsigned short*)(ws + ((size_t)8 << 20));
  unsigned short* B_t  = (unsigned short*)(ws + ((size_t)24 << 20));
  unsigned short* pre  = (unsigned short*)(ws + ((size_t)40 << 20));
  int* rows            = (int*)(ws + ((size_t)104 << 20));
  int* counts          = (int*)(ws + ((size_t)104 << 20) + 262144);

  cvt_x_kernel<<<4096, 256, 0, stream>>>(x, x_bf, 1048576);
  transpose_cvt_kernel<<<dim3(16, 32, 16), dim3(32, 8), 0, stream>>>(A, A_t, 1024, 512);
  transpose_cvt_kernel<<<dim3(32, 16, 16), dim3(32, 8), 0, stream>>>(B, B_t, 512, 1024);
  compact_kernel<<<16, 256, 0, stream>>>(mask, rows, counts);

  moe_gemm_kernel<0><<<dim3(4, 32, 16), 256, 0, stream>>>(x_bf, A_t, pre, nullptr, rows, counts);
  moe_gemm_kernel<1><<<dim3(8, 32, 16), 256, 0, stream>>>(pre, B_t, nullptr, inner, rows, counts);

  reduce_kernel<<<4096, 256, 0, stream>>>(inner, bias, mask, out);
}